// Round 8
// baseline (1254.420 us; speedup 1.0000x reference)
//
#include <hip/hip_runtime.h>
#include <hip/hip_bf16.h>

#define NB 16
#define NS 2048
#define NE 1024
#define NH 4
#define NDH 256

typedef __hip_bfloat16 bf16;
typedef __attribute__((ext_vector_type(8))) short short8;
typedef __attribute__((ext_vector_type(4))) float f32x4;
typedef __attribute__((ext_vector_type(16))) float f32x16;

typedef const __attribute__((address_space(1))) unsigned int gu32;
typedef __attribute__((address_space(3))) unsigned int lu32;

__device__ __forceinline__ short f2b(float f) {
  bf16 h = (bf16)f;
  return *(short*)&h;
}

__device__ __forceinline__ short8 cvt8(f32x4 a, f32x4 b) {
  short8 r;
  r[0] = f2b(a[0]); r[1] = f2b(a[1]); r[2] = f2b(a[2]); r[3] = f2b(a[3]);
  r[4] = f2b(b[0]); r[5] = f2b(b[1]); r[6] = f2b(b[2]); r[7] = f2b(b[3]);
  return r;
}

__device__ __forceinline__ unsigned pack2bf(float a, float b) {
  bf16 ha = (bf16)a, hb = (bf16)b;
  return (unsigned)(*(unsigned short*)&ha) | ((unsigned)(*(unsigned short*)&hb) << 16);
}

// ---------------- fp32 -> bf16 convert (x and w_in) ----------------
__global__ void cvt_bf16_kernel(const float* __restrict__ x, const float* __restrict__ w,
                                bf16* __restrict__ xb, bf16* __restrict__ wb) {
  const long NX8 = (long)NB * NS * NE / 8;
  const long NW8 = (long)3 * NE * NE / 8;
  const long total = NX8 + NW8;
  for (long i = (long)blockIdx.x * 256 + threadIdx.x; i < total; i += (long)gridDim.x * 256) {
    if (i < NX8) {
      const f32x4* p = (const f32x4*)(x + i * 8);
      *(short8*)(xb + i * 8) = cvt8(p[0], p[1]);
    } else {
      long j = i - NX8;
      const f32x4* p = (const f32x4*)(w + j * 8);
      *(short8*)(wb + j * 8) = cvt8(p[0], p[1]);
    }
  }
}

// ---- GEMM1 fast path: bf16 inputs, global_load_lds staging (m97 structure) ----
__global__ __launch_bounds__(256, 1) void gemm_qkvt_b(
    const bf16* __restrict__ A, const bf16* __restrict__ W,
    const float* __restrict__ bias, bf16* __restrict__ Qb,
    bf16* __restrict__ Kb, bf16* __restrict__ Vtg)
{
  __shared__ __attribute__((aligned(16))) char smem[36864];
  char* As = smem;           // 16 KB  [128 rows][128 B], chunk-swizzled
  char* Bs = smem + 16384;   // 16 KB
  const int tid = threadIdx.x;
  const int wave = tid >> 6;
  const int lane = tid & 63;
  const int quad = lane >> 4;
  const int col = lane & 15;
  const int wm = wave & 1, wn = wave >> 1;
  const long mBase = (long)blockIdx.x * 128;
  const long nBase = (long)blockIdx.y * 128;

  f32x4 acc[4][4];
#pragma unroll
  for (int i = 0; i < 4; ++i)
#pragma unroll
    for (int j = 0; j < 4; ++j) acc[i][j] = (f32x4){0.f, 0.f, 0.f, 0.f};

  const int lr = lane >> 3;                 // row sub-index within instr
  const int lc = (lane & 7) ^ lr;           // pre-swizzled source chunk

  for (int k0 = 0; k0 < NE; k0 += 64) {
#pragma unroll
    for (int i = 0; i < 4; ++i) {
      int r = (wave * 4 + i) * 8 + lr;
      const char* sa = (const char*)(A + (mBase + r) * NE + k0) + lc * 16;
      const char* sb = (const char*)(W + (nBase + r) * NE + k0) + lc * 16;
      __builtin_amdgcn_global_load_lds((gu32*)sa, (lu32*)(As + (wave * 4 + i) * 1024), 16, 0, 0);
      __builtin_amdgcn_global_load_lds((gu32*)sb, (lu32*)(Bs + (wave * 4 + i) * 1024), 16, 0, 0);
    }
    __syncthreads();
#pragma unroll
    for (int ks = 0; ks < 2; ++ks) {
      short8 af[4], bfr[4];
      int kc = ks * 4 + quad;
#pragma unroll
      for (int t = 0; t < 4; ++t) {
        int rowA = wm * 64 + t * 16 + col;
        int rowB = wn * 64 + t * 16 + col;
        af[t] = *(const short8*)(As + rowA * 128 + ((kc ^ (rowA & 7)) << 4));
        bfr[t] = *(const short8*)(Bs + rowB * 128 + ((kc ^ (rowB & 7)) << 4));
      }
#pragma unroll
      for (int i = 0; i < 4; ++i)
#pragma unroll
        for (int j = 0; j < 4; ++j)
          acc[i][j] = __builtin_amdgcn_mfma_f32_16x16x32_bf16(af[i], bfr[j], acc[i][j], 0, 0, 0);
    }
    __syncthreads();
  }

  bf16* T = (bf16*)smem;  // [128][136]
  if (nBase >= 2 * NE) {
#pragma unroll
    for (int j = 0; j < 4; ++j) {
      int n = wn * 64 + j * 16 + col;
      float bv = bias[nBase + n];
#pragma unroll
      for (int i = 0; i < 4; ++i) {
        int m = wm * 64 + i * 16 + quad * 4;
#pragma unroll
        for (int r = 0; r < 4; ++r)
          T[n * 136 + m + r] = (bf16)(acc[i][j][r] + bv);
      }
    }
    __syncthreads();
    long b = mBase >> 11;       // S = 2048
    long sOff = mBase & 2047;
    int v0 = (int)(nBase - 2 * NE);
#pragma unroll
    for (int t = 0; t < 8; ++t) {
      int idx = t * 256 + tid;
      int n = idx >> 4;
      int mc = idx & 15;
      short8 v = *(const short8*)(T + n * 136 + mc * 8);
      int g = v0 + n;
      int h = g >> 8, d = g & 255;
      *(short8*)(Vtg + ((b * NH + h) * NDH + d) * (long)NS + sOff + mc * 8) = v;
    }
  } else {
    bf16* dst = (nBase < NE) ? Qb : Kb;
    long nOff = (nBase < NE) ? nBase : nBase - NE;
#pragma unroll
    for (int j = 0; j < 4; ++j) {
      int n = wn * 64 + j * 16 + col;
      float bv = bias[nBase + n];
#pragma unroll
      for (int i = 0; i < 4; ++i) {
        int m = wm * 64 + i * 16 + quad * 4;
#pragma unroll
        for (int r = 0; r < 4; ++r)
          T[(m + r) * 136 + n] = (bf16)(acc[i][j][r] + bv);
      }
    }
    __syncthreads();
#pragma unroll
    for (int t = 0; t < 8; ++t) {
      int idx = t * 256 + tid;
      int m = idx >> 4;
      int c = idx & 15;
      short8 v = *(const short8*)(T + m * 136 + c * 8);
      *(short8*)(dst + (mBase + m) * NE + nOff + c * 8) = v;
    }
  }
}

// ---- GEMM1 fallback (fp32 inputs, reg-staged cvt) — used when ws is small ----
#define GST 72
__global__ __launch_bounds__(256, 1) void gemm_qkvt(
    const float* __restrict__ A, const float* __restrict__ W,
    const float* __restrict__ bias, bf16* __restrict__ Qb,
    bf16* __restrict__ Kb, bf16* __restrict__ Vtg)
{
  __shared__ __attribute__((aligned(16))) char smem[36864];
  bf16* As = (bf16*)smem;
  bf16* Bs = As + 128 * GST;
  const int tid = threadIdx.x;
  const int wave = tid >> 6;
  const int lane = tid & 63;
  const int quad = lane >> 4;
  const int col = lane & 15;
  const int wm = wave & 1, wn = wave >> 1;
  const long mBase = (long)blockIdx.x * 128;
  const long nBase = (long)blockIdx.y * 128;
  const int K = NE;

  f32x4 acc[4][4];
#pragma unroll
  for (int i = 0; i < 4; ++i)
#pragma unroll
    for (int j = 0; j < 4; ++j) acc[i][j] = (f32x4){0.f, 0.f, 0.f, 0.f};

  for (int k0 = 0; k0 < K; k0 += 64) {
    short8 va[4], vb[4];
#pragma unroll
    for (int it = 0; it < 4; ++it) {
      int idx = it * 256 + tid;
      int row = idx >> 3;
      int c = idx & 7;
      const f32x4* ap = (const f32x4*)(A + (mBase + row) * K + k0 + c * 8);
      const f32x4* wp = (const f32x4*)(W + (nBase + row) * K + k0 + c * 8);
      va[it] = cvt8(ap[0], ap[1]);
      vb[it] = cvt8(wp[0], wp[1]);
    }
    __syncthreads();
#pragma unroll
    for (int it = 0; it < 4; ++it) {
      int idx = it * 256 + tid;
      int row = idx >> 3;
      int c = idx & 7;
      *(short8*)(As + row * GST + c * 8) = va[it];
      *(short8*)(Bs + row * GST + c * 8) = vb[it];
    }
    __syncthreads();
#pragma unroll
    for (int ks = 0; ks < 2; ++ks) {
      short8 af[4], bfr[4];
#pragma unroll
      for (int t = 0; t < 4; ++t) {
        int rowA = wm * 64 + t * 16 + col;
        int rowB = wn * 64 + t * 16 + col;
        int kc = ks * 4 + quad;
        af[t] = *(const short8*)(As + rowA * GST + kc * 8);
        bfr[t] = *(const short8*)(Bs + rowB * GST + kc * 8);
      }
#pragma unroll
      for (int i = 0; i < 4; ++i)
#pragma unroll
        for (int j = 0; j < 4; ++j)
          acc[i][j] = __builtin_amdgcn_mfma_f32_16x16x32_bf16(af[i], bfr[j], acc[i][j], 0, 0, 0);
    }
  }

  if (nBase >= 2 * NE) {
    __syncthreads();
    bf16* T = (bf16*)smem;  // [128][136]
#pragma unroll
    for (int j = 0; j < 4; ++j) {
      int n = wn * 64 + j * 16 + col;
      float bv = bias[nBase + n];
#pragma unroll
      for (int i = 0; i < 4; ++i) {
        int m = wm * 64 + i * 16 + quad * 4;
#pragma unroll
        for (int r = 0; r < 4; ++r)
          T[n * 136 + m + r] = (bf16)(acc[i][j][r] + bv);
      }
    }
    __syncthreads();
    long b = mBase >> 11;
    long sOff = mBase & 2047;
    int v0 = (int)(nBase - 2 * NE);
#pragma unroll
    for (int t = 0; t < 8; ++t) {
      int idx = t * 256 + tid;
      int n = idx >> 4;
      int mc = idx & 15;
      short8 v = *(const short8*)(T + n * 136 + mc * 8);
      int g = v0 + n;
      int h = g >> 8, d = g & 255;
      *(short8*)(Vtg + ((b * NH + h) * NDH + d) * (long)NS + sOff + mc * 8) = v;
    }
  } else {
    bf16* dst = (nBase < NE) ? Qb : Kb;
    long nOff = (nBase < NE) ? nBase : nBase - NE;
#pragma unroll
    for (int j = 0; j < 4; ++j) {
      int nl = wn * 64 + j * 16 + col;
      float bv = bias[nBase + nl];
      long n = nOff + nl;
#pragma unroll
      for (int i = 0; i < 4; ++i) {
        long m0 = mBase + wm * 64 + i * 16 + quad * 4;
#pragma unroll
        for (int r = 0; r < 4; ++r)
          dst[(m0 + r) * NE + n] = (bf16)(acc[i][j][r] + bv);
      }
    }
  }
}

// ---------------- mask dtype probe ----------------
__global__ void probe_mask_kernel(const void* maskp, float* flags) {
  int i = blockIdx.x * 256 + threadIdx.x;  // 16384 threads
  const unsigned short* mh = (const unsigned short*)maskp;
  unsigned short hv = mh[i];
  if (hv != 0 && hv != 1 && hv != 0x3F80 && hv != 0x3C00)
    atomicAdd(&flags[1], 1.0f);
  if (i < 8192) {
    unsigned int v = ((const unsigned int*)maskp)[i];
    if (v != 0u && v != 1u) atomicAdd(&flags[0], 1.0f);
    if (v != 0u && v != 0x3F800000u) atomicAdd(&flags[2], 1.0f);
  }
}

// maskf[b,k] = valid ? 0 : -1e9  (additive score bias)
__global__ void prep_mask_kernel(const void* maskp, const float* __restrict__ flags,
                                 float* __restrict__ maskf) {
  int i = blockIdx.x * 256 + threadIdx.x;
  if (i >= NB * NS) return;
  int mmode;
  if (flags[0] == 0.f) mmode = 0;
  else if (flags[2] == 0.f) mmode = 3;
  else if (flags[1] == 0.f) mmode = 1;
  else mmode = 2;
  bool valid;
  if (mmode == 0) valid = ((const int*)maskp)[i] != 0;
  else if (mmode == 3) valid = ((const unsigned int*)maskp)[i] != 0u;
  else if (mmode == 1) valid = ((const unsigned short*)maskp)[i] != 0;
  else valid = ((const unsigned char*)maskp)[i] != 0;
  maskf[i] = valid ? 0.f : -1e9f;
}

// ---------------- single-kernel attention, 32x32 MFMA, swapped QK ----------
// R8: split MFMA accumulation into 2 independent chains (halve dep-latency),
// interleave softmax(sl) with PV(sl) MFMAs, 1 barrier/tile (stage-after-
// barrier dbuf), loop2 without cs_lds (per-wave atomics), invl via shfl.
#define QBLK 256
#define KBLK 32

__device__ __forceinline__ void stage_k32(const bf16* kbase, char* buf,
                                          int qw, int hi, int cl) {
#pragma unroll
  for (int i = 0; i < 2; ++i) {
    int c = qw * 2 + i;
    int row = 2 * c + hi;
    const char* src = (const char*)(kbase + (long)row * NE) + ((cl ^ (row & 7)) << 4);
    char* dst = buf + c * 1024;
    __builtin_amdgcn_global_load_lds((gu32*)src, (lu32*)dst, 16, 0, 0);
  }
}

__device__ __forceinline__ void stage_v32(const bf16* vbase, char* buf,
                                          int qw, int lane) {
#pragma unroll
  for (int i = 0; i < 2; ++i) {
    int c = qw * 2 + i;
    int d = c * 16 + (lane >> 2);
    int j0 = lane & 3;
    const char* src = (const char*)(vbase + (long)d * NS) + ((j0 ^ ((d >> 1) & 3)) << 4);
    char* dst = buf + c * 1024;
    __builtin_amdgcn_global_load_lds((gu32*)src, (lu32*)dst, 16, 0, 0);
  }
}

__global__ __launch_bounds__(512, 1) void attn_kernel(
    bf16* __restrict__ Qb, const bf16* __restrict__ Kb,
    const bf16* __restrict__ Vtg, const float* __restrict__ maskf,
    float* __restrict__ colsum)
{
  __shared__ __attribute__((aligned(16))) char Stage[65536];  // K dbuf 2x16K | V dbuf 2x16K

  const int tid = threadIdx.x;
  const int qw = tid >> 6;       // wave id 0..7
  const int lane = tid & 63;
  const int hi = lane >> 5;
  const int cl = lane & 31;

  // XCD-affine remap: xcd = n&7 is a function of (b,h) -> shared K/V panels
  // are L2-resident per XCD. Bijective over 512.
  int n = blockIdx.x + 8 * blockIdx.y + 32 * blockIdx.z;  // 0..511
  const int qc = (n >> 3) & 7;
  int grp = ((n >> 6) << 3) | (n & 7);   // 0..63 = b*4+h
  const int h = grp & 3;
  const int b = grp >> 2;

  const int qBase = qc * QBLK;
  const long qkRow = (long)b * NS;
  const long vBase = ((long)(b * NH + h)) * NDH * NS;
  const float* mrow = maskf + b * NS;
  const float c1 = 0.09016844f;  // log2(e)/16

  // valid-tile count (mask monotone; tile dead iff first key masked)
  int ntv;
  {
    float mv = mrow[lane * KBLK];
    unsigned long long bm = __ballot(mv != 0.f);
    ntv = (bm == 0ULL) ? (NS / KBLK) : (__ffsll((long long)bm) - 1);
    if (ntv < 1) ntv = 1;
  }

  // ---- Q fragments to registers via 2 LDS rounds (coalesced stage) ----
  short8 bq[16];
  {
    char* SB = Stage;
    for (int r = 0; r < 2; ++r) {
#pragma unroll
      for (int i = 0; i < 8; ++i) {
        int c = qw * 8 + i;
        int row = 2 * c + hi;
        const char* src = (const char*)(Qb + (qkRow + qBase + r * 128 + row) * NE + h * NDH)
                          + ((cl ^ (row & 7)) << 4);
        __builtin_amdgcn_global_load_lds((gu32*)src, (lu32*)(SB + c * 1024), 16, 0, 0);
      }
      __syncthreads();
      if ((qw >> 2) == r) {
        int lrow = (qw & 3) * 32 + cl;
        int sw = lrow & 7;
#pragma unroll
        for (int s16 = 0; s16 < 16; ++s16)
          bq[s16] = *(const short8*)(SB + lrow * 512 + (((2 * s16 + hi) ^ sw) << 4));
      }
      __syncthreads();
    }
  }

  char* KB0 = Stage;
  char* KB1 = Stage + 16384;
  char* VB0 = Stage + 32768;
  char* VB1 = Stage + 49152;

  f32x16 acc[8];
#pragma unroll
  for (int db = 0; db < 8; ++db)
#pragma unroll
    for (int r = 0; r < 16; ++r) acc[db][r] = 0.f;
  float l_acc = 0.f;

  // prologue: stage tile 0 only (stage-after-barrier dbuf, depth 1)
  stage_k32(Kb + qkRow * NE + h * NDH, KB0, qw, hi, cl);
  stage_v32(Vtg + vBase, VB0, qw, lane);

  const int swr = cl & 7;

  // ---------------- loop 1: QK^T (swapped) + P + PV, 1 barrier/tile --------
  for (int kt = 0; kt < ntv; ++kt) {
    asm volatile("s_waitcnt vmcnt(0)" ::: "memory");   // own stage(kt) landed
    __builtin_amdgcn_sched_barrier(0);
    __builtin_amdgcn_s_barrier();                      // all staged; all done reading kt-1
    __builtin_amdgcn_sched_barrier(0);
    if (kt + 1 <= 63) {   // prefetch next tile (memory always valid)
      stage_k32(Kb + (qkRow + (kt + 1) * KBLK) * NE + h * NDH,
                (kt & 1) ? KB0 : KB1, qw, hi, cl);
      stage_v32(Vtg + vBase + (kt + 1) * KBLK, (kt & 1) ? VB0 : VB1, qw, lane);
    }
    char* KC = (kt & 1) ? KB1 : KB0;
    char* VC = (kt & 1) ? VB1 : VB0;
    // QK: D[k][q] = K.Q^T ; lane owns q = cl.  2 independent MFMA chains.
    f32x16 sA, sB;
#pragma unroll
    for (int r = 0; r < 16; ++r) { sA[r] = 0.f; sB[r] = 0.f; }
    __builtin_amdgcn_s_setprio(1);
#pragma unroll
    for (int u = 0; u < 8; ++u) {
      short8 kf0 = *(const short8*)(KC + cl * 512 + (((4 * u + hi) ^ swr) << 4));
      short8 kf1 = *(const short8*)(KC + cl * 512 + (((4 * u + 2 + hi) ^ swr) << 4));
      sA = __builtin_amdgcn_mfma_f32_32x32x16_bf16(kf0, bq[2 * u], sA, 0, 0, 0);
      sB = __builtin_amdgcn_mfma_f32_32x32x16_bf16(kf1, bq[2 * u + 1], sB, 0, 0, 0);
    }
    __builtin_amdgcn_s_setprio(0);
#pragma unroll
    for (int r = 0; r < 16; ++r) sA[r] += sB[r];
    // softmax(sl) interleaved with PV(sl): VALU of one half overlaps MFMA of other
    bool bnd = (kt == ntv - 1);
#pragma unroll
    for (int sl = 0; sl < 2; ++sl) {
      float ex[8];
#pragma unroll
      for (int j = 0; j < 8; ++j) {
        float m2 = 0.f;
        if (bnd) {
          int row = (j & 3) + 16 * sl + 8 * (j >> 2) + 4 * hi;
          m2 = mrow[kt * 32 + row] * 1.4426950f;
        }
        ex[j] = exp2f(fmaf(sA[8 * sl + j], c1, m2));
        l_acc += ex[j];
      }
      unsigned pka = pack2bf(ex[0], ex[1]), pkb = pack2bf(ex[2], ex[3]);
      unsigned pkc = pack2bf(ex[4], ex[5]), pkd = pack2bf(ex[6], ex[7]);
      unsigned swa = __shfl_xor(pka, 32), swb = __shfl_xor(pkb, 32);
      unsigned swc = __shfl_xor(pkc, 32), swd = __shfl_xor(pkd, 32);
      union { unsigned u[4]; short8 s8; } U;
      U.u[0] = hi ? swc : pka;
      U.u[1] = hi ? swd : pkb;
      U.u[2] = hi ? pkc : swa;
      U.u[3] = hi ? pkd : swb;
      short8 pa = U.s8;
      __builtin_amdgcn_s_setprio(1);
#pragma unroll
      for (int db = 0; db < 8; ++db) {
        int d = db * 32 + cl;
        short8 vb = *(const short8*)(VC + d * 64 + (((sl * 2 + hi) ^ ((d >> 1) & 3)) << 4));
        acc[db] = __builtin_amdgcn_mfma_f32_32x32x16_bf16(pa, vb, acc[db], 0, 0, 0);
      }
      __builtin_amdgcn_s_setprio(0);
    }
  }

  // ---- quiesce loop1 (pending prefetch of tile ntv drains here) ----
  asm volatile("s_waitcnt vmcnt(0) lgkmcnt(0)" ::: "memory");
  __builtin_amdgcn_sched_barrier(0);
  __builtin_amdgcn_s_barrier();
  __builtin_amdgcn_sched_barrier(0);

  // invl entirely in registers: lane q holds l[q]; fetch via shuffle
  float invlr[16];
  {
    float lt = l_acc + __shfl_xor(l_acc, 32);
    float inv_lt = 1.0f / lt;
#pragma unroll
    for (int r = 0; r < 16; ++r)
      invlr[r] = __shfl(inv_lt, (r & 3) + 8 * (r >> 2) + 4 * hi);
  }

  // epilogue: ctx in place into Qb (sole reader of these rows was this block)
  {
    bf16* base = Qb + (qkRow + qBase + qw * 32) * NE + h * NDH;
#pragma unroll
    for (int db = 0; db < 8; ++db)
#pragma unroll
      for (int r = 0; r < 16; ++r) {
        int row = (r & 3) + 8 * (r >> 2) + 4 * hi;
        base[(long)row * NE + db * 32 + cl] = (bf16)(acc[db][r] * invlr[r]);
      }
  }

  // ---------------- loop 2: colsum (QK unswapped; lane owns k = cl) --------
  stage_k32(Kb + qkRow * NE + h * NDH, KB0, qw, hi, cl);  // prologue
  for (int kt = 0; kt < ntv; ++kt) {
    if (kt == 0) asm volatile("s_waitcnt vmcnt(0)" ::: "memory");  // + ctx stores
    else         asm volatile("s_waitcnt vmcnt(1)" ::: "memory");  // leave atomic
    __builtin_amdgcn_sched_barrier(0);
    __builtin_amdgcn_s_barrier();
    __builtin_amdgcn_sched_barrier(0);
    if (kt + 1 <= 63)
      stage_k32(Kb + (qkRow + (kt + 1) * KBLK) * NE + h * NDH,
                (kt & 1) ? KB0 : KB1, qw, hi, cl);
    char* KC = (kt & 1) ? KB1 : KB0;
    f32x16 sA, sB;
#pragma unroll
    for (int r = 0; r < 16; ++r) { sA[r] = 0.f; sB[r] = 0.f; }
    __builtin_amdgcn_s_setprio(1);
#pragma unroll
    for (int u = 0; u < 8; ++u) {
      short8 kf0 = *(const short8*)(KC + cl * 512 + (((4 * u + hi) ^ swr) << 4));
      short8 kf1 = *(const short8*)(KC + cl * 512 + (((4 * u + 2 + hi) ^ swr) << 4));
      sA = __builtin_amdgcn_mfma_f32_32x32x16_bf16(bq[2 * u], kf0, sA, 0, 0, 0);
      sB = __builtin_amdgcn_mfma_f32_32x32x16_bf16(bq[2 * u + 1], kf1, sB, 0, 0, 0);
    }
    __builtin_amdgcn_s_setprio(0);
    float mb2 = (kt == ntv - 1) ? mrow[kt * 32 + cl] * 1.4426950f : 0.f;
    float cs = 0.f;
#pragma unroll
    for (int r = 0; r < 16; ++r)
      cs += exp2f(fmaf(sA[r] + sB[r], c1, mb2)) * invlr[r];
    cs += __shfl_xor(cs, 32);
    if (lane < 32)
      atomicAdd(&colsum[b * NS + kt * 32 + lane], cs);
  }
}

// ---------------- tails ----------------
__global__ void zero_ws_kernel(float* __restrict__ colsum, float* __restrict__ g,
                               float* __restrict__ flags) {
  int i = blockIdx.x * 256 + threadIdx.x;
  if (i < NB * NS) colsum[i] = 0.f;
  if (i < NB * NE) g[i] = 0.f;
  if (i < 16) flags[i] = 0.f;
}

// g[b,f] += sum_{s in chunk} colsum[b,s] * ctx[b,s,f]  (ctx in Qb, stride E)
__global__ void weighted_ctx_kernel(const float* __restrict__ colsum,
                                    const bf16* __restrict__ Qb,
                                    float* __restrict__ g) {
  int b = blockIdx.y;
  int f = blockIdx.x * 256 + threadIdx.x;
  int s0 = blockIdx.z * 256;
  float acc = 0.f;
  for (int s = s0; s < s0 + 256; ++s)
    acc += colsum[b * NS + s] * (float)Qb[((long)(b * NS + s)) * NE + f];
  atomicAdd(&g[b * NE + f], acc);
}

// out[b,e] = (1/H) * sum_f g[b,f]*Wout[e,f] + S * bout[e]
__global__ void final_gemv_kernel(const float* __restrict__ g,
                                  const float* __restrict__ w_out,
                                  const float* __restrict__ b_out,
                                  float* __restrict__ out) {
  __shared__ float gs[NE];
  int b = blockIdx.y;
  int e = blockIdx.x * 256 + threadIdx.x;
  for (int i = threadIdx.x; i < NE; i += 256) gs[i] = g[b * NE + i];
  __syncthreads();
  float acc = 0.f;
  for (int f = 0; f < NE; f += 4) {
    f32x4 w = *(const f32x4*)(w_out + (long)e * NE + f);
    acc += gs[f + 0] * w[0] + gs[f + 1] * w[1] + gs[f + 2] * w[2] + gs[f + 3] * w[3];
  }
  out[b * NE + e] = acc * (1.0f / NH) + (float)NS * b_out[e];
}

__global__ void sentinel_kernel(float* __restrict__ out, float v) {
  int i = blockIdx.x * 256 + threadIdx.x;
  if (i < NB * NE) out[i] = v;
}

extern "C" void kernel_launch(void* const* d_in, const int* in_sizes, int n_in,
                              void* d_out, int out_size, void* d_ws, size_t ws_size,
                              hipStream_t stream) {
  const float* x     = (const float*)d_in[0];
  const void*  maskp = d_in[1];
  const float* w_in  = (const float*)d_in[2];
  const float* b_in  = (const float*)d_in[3];
  const float* w_out = (const float*)d_in[4];
  const float* b_out = (const float*)d_in[5];
  float* out = (float*)d_out;

  bool ok_sizes = (n_in == 6) &&
                  in_sizes[0] == NB * NS * NE && in_sizes[1] == NB * NS &&
                  in_sizes[2] == 3 * NE * NE && in_sizes[3] == 3 * NE &&
                  in_sizes[4] == NE * NE && in_sizes[5] == NE &&
                  out_size == NB * NE;
  if (!ok_sizes) {
    sentinel_kernel<<<dim3(64), dim3(256), 0, stream>>>(out, 222.0f);
    return;
  }
  const size_t NEED = 201326592ULL + 131072ULL + 65536ULL + 64ULL + 131072ULL;  // 201,654,336
  if (ws_size < NEED) {
    sentinel_kernel<<<dim3(64), dim3(256), 0, stream>>>(out, 111.0f);
    return;
  }
  // fast path extra: xb (67,108,864) + wb (6,291,456)
  const size_t NEED2 = NEED + 67108864ULL + 6291456ULL;  // 275,054,656

  char* ws = (char*)d_ws;
  bf16* Qb      = (bf16*)ws;                    // 67,108,864 B
  bf16* Kb      = (bf16*)(ws + 67108864);       // 67,108,864 B
  bf16* Vtg     = (bf16*)(ws + 134217728);      // 67,108,864 B  [B,H,DH,S]
  float* colsum = (float*)(ws + 201326592);     // 131,072 B
  float* g      = (float*)(ws + 201457664);     // 65,536 B
  float* flags  = (float*)(ws + 201523200);     // 64 B
  float* maskf  = (float*)(ws + 201523264);     // 131,072 B
  bf16* xb      = (bf16*)(ws + 201654336);      // 67,108,864 B (fast path)
  bf16* wb      = (bf16*)(ws + 268763200);      // 6,291,456 B  (fast path)

  zero_ws_kernel<<<dim3(128), dim3(256), 0, stream>>>(colsum, g, flags);
  probe_mask_kernel<<<dim3(64), dim3(256), 0, stream>>>(maskp, flags);
  prep_mask_kernel<<<dim3(128), dim3(256), 0, stream>>>(maskp, flags, maskf);
  if (ws_size >= NEED2) {
    cvt_bf16_kernel<<<dim3(2048), dim3(256), 0, stream>>>(x, w_in, xb, wb);
    gemm_qkvt_b<<<dim3(256, 24), dim3(256), 0, stream>>>(xb, wb, b_in, Qb, Kb, Vtg);
  } else {
    gemm_qkvt<<<dim3(256, 24), dim3(256), 0, stream>>>(x, w_in, b_in, Qb, Kb, Vtg);
  }
  attn_kernel<<<dim3(8, NH, NB), dim3(512), 0, stream>>>(Qb, Kb, Vtg, maskf, colsum);
  weighted_ctx_kernel<<<dim3(NE / 256, NB, NS / 256), dim3(256), 0, stream>>>(colsum, Qb, g);
  final_gemv_kernel<<<dim3(NE / 256, NB), dim3(256), 0, stream>>>(g, w_out, b_out, out);
}